// Round 1
// baseline (1499.175 us; speedup 1.0000x reference)
//
#include <hip/hip_runtime.h>

#define S 2048
#define DD 64
#define NW 8            // waves per block
#define KSLICE 256      // k columns per wave
#define NT 16           // 16-wide k tiles per wave

typedef float f32x4 __attribute__((ext_vector_type(4)));
typedef short bf16x8 __attribute__((ext_vector_type(8)));

__device__ inline float bf16f(unsigned short h){
  return __uint_as_float(((unsigned int)h) << 16);
}
// truncation split: x ~= hi + lo, each bf16; combined ~16-bit mantissa
__device__ inline void split2(float x, short &hi, short &lo){
  unsigned int u = __float_as_uint(x);
  unsigned short h = (unsigned short)(u >> 16);
  float rem = x - bf16f(h);
  hi = (short)h;
  lo = (short)(unsigned short)(__float_as_uint(rem) >> 16);
}

__global__ __launch_bounds__(512, 2)
void attn_fused_kernel(const float* __restrict__ q, const float* __restrict__ k,
                       const float* __restrict__ v, const float* __restrict__ bias,
                       const float* __restrict__ gb, float* __restrict__ out,
                       float* __restrict__ wout)
{
  const int head = blockIdx.y;            // 0..31 (b*H+h)
  const int q0   = blockIdx.x * 16;       // q-tile base row
  const int tid  = threadIdx.x;
  const int wid  = tid >> 6;
  const int lane = tid & 63;
  const int lr   = lane & 15;             // 0..15
  const int lg   = lane >> 4;             // 0..3

  const float* qh = q    + (size_t)head * S * DD;
  const float* kh = k    + (size_t)head * S * DD;
  const float* vh = v    + (size_t)head * S * DD;
  const float* bh = bias + (size_t)head * S * S;
  const float* gh = gb   + (size_t)head * S * S;
  float* oh = out  + (size_t)head * S * DD;
  float* wh = wout + (size_t)head * S * S;

  __shared__ unsigned int sW[NW][16][68];   // packed (hi<<16)|lo bf16 weights, padded
  __shared__ float redm[NW][16];
  __shared__ float redl[NW][16];

  // ---- Q fragments (A operand: lane holds Q[q0+lr][lg*8+j (+32*ks)]), pre-scaled
  bf16x8 qhi[2], qlo[2];
  {
    const float* qrow = qh + (size_t)(q0 + lr) * DD;
#pragma unroll
    for (int ks = 0; ks < 2; ++ks){
      float4 a = *reinterpret_cast<const float4*>(qrow + ks*32 + lg*8);
      float4 b = *reinterpret_cast<const float4*>(qrow + ks*32 + lg*8 + 4);
      float f[8] = {a.x,a.y,a.z,a.w,b.x,b.y,b.z,b.w};
#pragma unroll
      for (int j = 0; j < 8; ++j){
        short h, l2;
        split2(f[j] * 0.125f, h, l2);
        qhi[ks][j] = h; qlo[ks][j] = l2;
      }
    }
  }

  const int kw0 = wid * KSLICE;
  f32x4 acc[NT];
#pragma unroll
  for (int t = 0; t < NT; ++t) acc[t] = (f32x4){0.f,0.f,0.f,0.f};

  // ---- Phase 1: scores = (q*scale)K^T + bias - 0.5*g^2
#pragma unroll 2
  for (int t = 0; t < NT; ++t){
    const int kbase = kw0 + 16*t;
    const float* krow = kh + (size_t)(kbase + lr) * DD;
#pragma unroll
    for (int ks = 0; ks < 2; ++ks){
      float4 a = *reinterpret_cast<const float4*>(krow + ks*32 + lg*8);
      float4 b = *reinterpret_cast<const float4*>(krow + ks*32 + lg*8 + 4);
      float f[8] = {a.x,a.y,a.z,a.w,b.x,b.y,b.z,b.w};
      bf16x8 bhi, blo;
#pragma unroll
      for (int j = 0; j < 8; ++j){
        short h, l2; split2(f[j], h, l2);
        bhi[j] = h; blo[j] = l2;
      }
      acc[t] = __builtin_amdgcn_mfma_f32_16x16x32_bf16(qlo[ks], bhi, acc[t], 0,0,0);
      acc[t] = __builtin_amdgcn_mfma_f32_16x16x32_bf16(qhi[ks], blo, acc[t], 0,0,0);
      acc[t] = __builtin_amdgcn_mfma_f32_16x16x32_bf16(qhi[ks], bhi, acc[t], 0,0,0);
    }
    const int col = kbase + lr;
#pragma unroll
    for (int r = 0; r < 4; ++r){
      const size_t idx = (size_t)(q0 + lg*4 + r) * S + col;
      float sb = bh[idx];
      float sg = gh[idx];
      acc[t][r] += sb - 0.5f * sg * sg;
    }
  }

  // ---- Phase 2: softmax (row = q0 + lg*4 + r lives in 16 lanes sharing lg, across 8 waves)
  float m[4];
#pragma unroll
  for (int r = 0; r < 4; ++r){
    float mm = acc[0][r];
#pragma unroll
    for (int t = 1; t < NT; ++t) mm = fmaxf(mm, acc[t][r]);
#pragma unroll
    for (int off = 1; off < 16; off <<= 1) mm = fmaxf(mm, __shfl_xor(mm, off, 64));
    m[r] = mm;
  }
  if (lr < 4) redm[wid][lg*4 + lr] = m[lr];
  __syncthreads();
#pragma unroll
  for (int r = 0; r < 4; ++r){
    float mm = redm[0][lg*4 + r];
#pragma unroll
    for (int w = 1; w < NW; ++w) mm = fmaxf(mm, redm[w][lg*4 + r]);
    m[r] = mm;
  }

  float lsum[4];
#pragma unroll
  for (int r = 0; r < 4; ++r){
    float s = 0.f;
#pragma unroll
    for (int t = 0; t < NT; ++t){
      float e = __expf(acc[t][r] - m[r]);
      acc[t][r] = e;
      s += e;
    }
#pragma unroll
    for (int off = 1; off < 16; off <<= 1) s += __shfl_xor(s, off, 64);
    lsum[r] = s;
  }
  if (lr < 4) redl[wid][lg*4 + lr] = lsum[lr];
  __syncthreads();
  float inv[4];
#pragma unroll
  for (int r = 0; r < 4; ++r){
    float s = 0.f;
#pragma unroll
    for (int w = 0; w < NW; ++w) s += redl[w][lg*4 + r];
    inv[r] = 1.0f / s;
  }

  // ---- Phase 3: normalize in-regs and write weights (fp32, exact layout of D-frag)
#pragma unroll 2
  for (int t = 0; t < NT; ++t){
    const int col = kw0 + 16*t + lr;
#pragma unroll
    for (int r = 0; r < 4; ++r){
      float w = acc[t][r] * inv[r];
      acc[t][r] = w;
      wh[(size_t)(q0 + lg*4 + r) * S + col] = w;
    }
  }

  // ---- Phase 4: PV with hi/lo split, per-wave partial over its k-slice
  f32x4 oacc[4];
#pragma unroll
  for (int n = 0; n < 4; ++n) oacc[n] = (f32x4){0.f,0.f,0.f,0.f};

#pragma unroll 1
  for (int c = 0; c < 4; ++c){            // 64-k chunks within this wave's slice
    // repack this chunk's weights into per-wave LDS tile (u32 = hi<<16 | lo)
#pragma unroll
    for (int tt = 0; tt < 4; ++tt){
      int t = 4*c + tt;
#pragma unroll
      for (int r = 0; r < 4; ++r){
        float w = acc[t][r];
        short h, l2; split2(w, h, l2);
        sW[wid][lg*4 + r][16*tt + lr] =
            ((unsigned int)(unsigned short)h << 16) | (unsigned int)(unsigned short)l2;
      }
    }
    const int kc = kw0 + 64*c;
#pragma unroll
    for (int ks = 0; ks < 2; ++ks){
      unsigned int p[8];
#pragma unroll
      for (int j = 0; j < 8; ++j) p[j] = sW[wid][lr][32*ks + lg*8 + j];
      bf16x8 ahi, alo;
#pragma unroll
      for (int j = 0; j < 8; ++j){
        ahi[j] = (short)(p[j] >> 16);
        alo[j] = (short)(p[j] & 0xFFFFu);
      }
#pragma unroll
      for (int n = 0; n < 4; ++n){
        bf16x8 bhi, blo;
#pragma unroll
        for (int j = 0; j < 8; ++j){
          float x = vh[(size_t)(kc + 32*ks + lg*8 + j) * DD + 16*n + lr];
          short h, l2; split2(x, h, l2);
          bhi[j] = h; blo[j] = l2;
        }
        oacc[n] = __builtin_amdgcn_mfma_f32_16x16x32_bf16(alo, bhi, oacc[n], 0,0,0);
        oacc[n] = __builtin_amdgcn_mfma_f32_16x16x32_bf16(ahi, blo, oacc[n], 0,0,0);
        oacc[n] = __builtin_amdgcn_mfma_f32_16x16x32_bf16(ahi, bhi, oacc[n], 0,0,0);
      }
    }
  }

  // ---- Phase 5: cross-wave reduction of out partials through LDS (alias sW)
  float (*sO)[16][68] = reinterpret_cast<float(*)[16][68]>(sW);
#pragma unroll
  for (int n = 0; n < 4; ++n)
#pragma unroll
    for (int r = 0; r < 4; ++r)
      sO[wid][lg*4 + r][16*n + lr] = oacc[n][r];
  __syncthreads();
#pragma unroll
  for (int i = tid; i < 16*64; i += 512){
    int row = i >> 6, d = i & 63;
    float s = 0.f;
#pragma unroll
    for (int w = 0; w < NW; ++w) s += sO[w][row][d];
    oh[(size_t)(q0 + row) * DD + d] = s;
  }
}

extern "C" void kernel_launch(void* const* d_in, const int* in_sizes, int n_in,
                              void* d_out, int out_size, void* d_ws, size_t ws_size,
                              hipStream_t stream) {
  const float* q    = (const float*)d_in[0];
  const float* k    = (const float*)d_in[1];
  const float* v    = (const float*)d_in[2];
  const float* bias = (const float*)d_in[3];
  const float* gb   = (const float*)d_in[4];
  float* out  = (float*)d_out;                         // [4,8,2048,64]
  float* wout = (float*)d_out + (size_t)4*8*2048*64;   // [4,8,2048,2048]

  dim3 grid(S / 16, 32);
  dim3 block(512);
  attn_fused_kernel<<<grid, block, 0, stream>>>(q, k, v, bias, gb, out, wout);
}

// Round 2
// 1229.397 us; speedup vs baseline: 1.2194x; 1.2194x over previous
//
#include <hip/hip_runtime.h>

#define S 2048
#define DD 64
#define NH 32           // B*H
#define NW 8            // waves per block
#define KSLICE 256      // k columns per wave
#define NT 16           // 16-wide k tiles per wave

typedef float f32x4 __attribute__((ext_vector_type(4)));
typedef short bf16x8 __attribute__((ext_vector_type(8)));

__device__ inline unsigned int packsplit(float x){
  unsigned int u = __float_as_uint(x);
  unsigned int h = u >> 16;
  float rem = x - __uint_as_float(h << 16);
  unsigned int l = __float_as_uint(rem) >> 16;
  return (h << 16) | l;
}
__device__ inline void split2(float x, short &hi, short &lo){
  unsigned int p = packsplit(x);
  hi = (short)(p >> 16); lo = (short)(p & 0xFFFFu);
}

// ---- pre-pack kernels ----
__global__ void pack_k_kernel(const float* __restrict__ in, unsigned int* __restrict__ out, int n4){
  int i = blockIdx.x * 256 + threadIdx.x;
  if (i < n4){
    float4 x = reinterpret_cast<const float4*>(in)[i];
    uint4 p;
    p.x = packsplit(x.x); p.y = packsplit(x.y);
    p.z = packsplit(x.z); p.w = packsplit(x.w);
    reinterpret_cast<uint4*>(out)[i] = p;
  }
}

__global__ void pack_vt_kernel(const float* __restrict__ v, unsigned int* __restrict__ vt){
  const int head = blockIdx.x >> 5;
  const int s0   = (blockIdx.x & 31) * 64;
  const float* vh = v + (size_t)head * S * DD;
  unsigned int* vth = vt + (size_t)head * DD * S;
  __shared__ unsigned int tile[64][65];
  const int tid = threadIdx.x;
  for (int i = tid; i < 64*64; i += 256){
    int s = i >> 6, d = i & 63;
    tile[d][s] = packsplit(vh[(size_t)(s0 + s) * DD + d]);
  }
  __syncthreads();
  for (int i = tid; i < 64*64; i += 256){
    int d = i >> 6, s = i & 63;
    vth[(size_t)d * S + s0 + s] = tile[d][s];
  }
}

// ---- fused attention ----
template<bool PACKED>
__global__ __launch_bounds__(512, 2)
void attn_fused_kernel(const float* __restrict__ q, const float* __restrict__ k,
                       const float* __restrict__ v, const float* __restrict__ bias,
                       const float* __restrict__ gb,
                       const unsigned int* __restrict__ kp,
                       const unsigned int* __restrict__ vtp,
                       float* __restrict__ out, float* __restrict__ wout)
{
  const int head = blockIdx.y;
  const int q0   = blockIdx.x * 16;
  const int tid  = threadIdx.x;
  const int wid  = tid >> 6;
  const int lane = tid & 63;
  const int lr   = lane & 15;
  const int lg   = lane >> 4;

  const float* qh = q    + (size_t)head * S * DD;
  const float* kh = k    + (size_t)head * S * DD;
  const float* vh = v    + (size_t)head * S * DD;
  const float* bh = bias + (size_t)head * S * S;
  const float* gh = gb   + (size_t)head * S * S;
  const unsigned int* kph  = kp  + (size_t)head * S * DD;
  const unsigned int* vtph = vtp + (size_t)head * DD * S;
  float* oh = out  + (size_t)head * S * DD;
  float* wh = wout + (size_t)head * S * S;

  __shared__ unsigned int sW[NW][16][68];
  __shared__ float redm[NW][16];
  __shared__ float redl[NW][16];

  // ---- Q fragments (B operand: lane holds Q[q0+lr][32ks + lg*8+j]), pre-scaled
  bf16x8 qhi[2], qlo[2];
  {
    const float* qrow = qh + (size_t)(q0 + lr) * DD;
#pragma unroll
    for (int ks = 0; ks < 2; ++ks){
      float4 a = *reinterpret_cast<const float4*>(qrow + ks*32 + lg*8);
      float4 b = *reinterpret_cast<const float4*>(qrow + ks*32 + lg*8 + 4);
      float f[8] = {a.x,a.y,a.z,a.w,b.x,b.y,b.z,b.w};
#pragma unroll
      for (int j = 0; j < 8; ++j){
        short h, l2; split2(f[j] * 0.125f, h, l2);
        qhi[ks][j] = h; qlo[ks][j] = l2;
      }
    }
  }

  const int kw0 = wid * KSLICE;
  f32x4 acc[NT];
#pragma unroll
  for (int t = 0; t < NT; ++t) acc[t] = (f32x4){0.f,0.f,0.f,0.f};

  const float* brow = bh + (size_t)(q0 + lr) * S + kw0 + lg*4;
  const float* grow = gh + (size_t)(q0 + lr) * S + kw0 + lg*4;

  // ---- Phase 1: scores^T tile: lane holds S[q0+lr][kw0+16t+lg*4+r]
#pragma unroll 2
  for (int t = 0; t < NT; ++t){
    const int kbase = kw0 + 16*t;
    bf16x8 khi[2], klo[2];
    if constexpr (PACKED){
      const unsigned int* kr = kph + (size_t)(kbase + lr) * DD;
#pragma unroll
      for (int ks = 0; ks < 2; ++ks){
        uint4 p0 = *reinterpret_cast<const uint4*>(kr + ks*32 + lg*8);
        uint4 p1 = *reinterpret_cast<const uint4*>(kr + ks*32 + lg*8 + 4);
        unsigned int pw[8] = {p0.x,p0.y,p0.z,p0.w,p1.x,p1.y,p1.z,p1.w};
#pragma unroll
        for (int j = 0; j < 8; ++j){
          khi[ks][j] = (short)(pw[j] >> 16);
          klo[ks][j] = (short)(pw[j] & 0xFFFFu);
        }
      }
    } else {
      const float* krow = kh + (size_t)(kbase + lr) * DD;
#pragma unroll
      for (int ks = 0; ks < 2; ++ks){
        float4 a = *reinterpret_cast<const float4*>(krow + ks*32 + lg*8);
        float4 b = *reinterpret_cast<const float4*>(krow + ks*32 + lg*8 + 4);
        float f[8] = {a.x,a.y,a.z,a.w,b.x,b.y,b.z,b.w};
#pragma unroll
        for (int j = 0; j < 8; ++j){
          short h, l2; split2(f[j], h, l2);
          khi[ks][j] = h; klo[ks][j] = l2;
        }
      }
    }
#pragma unroll
    for (int ks = 0; ks < 2; ++ks){
      acc[t] = __builtin_amdgcn_mfma_f32_16x16x32_bf16(klo[ks], qhi[ks], acc[t], 0,0,0);
      acc[t] = __builtin_amdgcn_mfma_f32_16x16x32_bf16(khi[ks], qlo[ks], acc[t], 0,0,0);
      acc[t] = __builtin_amdgcn_mfma_f32_16x16x32_bf16(khi[ks], qhi[ks], acc[t], 0,0,0);
    }
    f32x4 b4 = *reinterpret_cast<const f32x4*>(brow + 16*t);
    f32x4 g4 = *reinterpret_cast<const f32x4*>(grow + 16*t);
#pragma unroll
    for (int r = 0; r < 4; ++r)
      acc[t][r] += b4[r] - 0.5f * g4[r] * g4[r];
  }

  // ---- Phase 2: softmax. Row q0+lr is fully owned along (lg, r, t, wave).
  float mrow;
  {
    float mm = -3.4e38f;
#pragma unroll
    for (int t = 0; t < NT; ++t)
#pragma unroll
      for (int r = 0; r < 4; ++r) mm = fmaxf(mm, acc[t][r]);
    mm = fmaxf(mm, __shfl_xor(mm, 16, 64));
    mm = fmaxf(mm, __shfl_xor(mm, 32, 64));
    if (lane < 16) redm[wid][lane] = mm;
  }
  __syncthreads();
  {
    float mm = redm[0][lr];
#pragma unroll
    for (int w = 1; w < NW; ++w) mm = fmaxf(mm, redm[w][lr]);
    mrow = mm;
  }

  float inv;
  {
    float s = 0.f;
#pragma unroll
    for (int t = 0; t < NT; ++t)
#pragma unroll
      for (int r = 0; r < 4; ++r){
        float e = __expf(acc[t][r] - mrow);
        acc[t][r] = e;
        s += e;
      }
    s += __shfl_xor(s, 16, 64);
    s += __shfl_xor(s, 32, 64);
    if (lane < 16) redl[wid][lane] = s;
    __syncthreads();
    float tot = 0.f;
#pragma unroll
    for (int w = 0; w < NW; ++w) tot += redl[w][lr];
    inv = 1.0f / tot;
  }

  // ---- Phase 3+4: normalize, write weights (float4), PV per 64-col chunk
  f32x4 oacc[4];
#pragma unroll
  for (int n = 0; n < 4; ++n) oacc[n] = (f32x4){0.f,0.f,0.f,0.f};

  float* wrow = wh + (size_t)(q0 + lr) * S + kw0 + lg*4;

#pragma unroll 1
  for (int c = 0; c < 4; ++c){
#pragma unroll
    for (int tt = 0; tt < 4; ++tt){
      const int t = 4*c + tt;
      f32x4 w4; uint4 pw;
#pragma unroll
      for (int r = 0; r < 4; ++r){
        float w = acc[t][r] * inv;
        w4[r] = w;
        (&pw.x)[r] = packsplit(w);
      }
      *reinterpret_cast<f32x4*>(wrow + 16*t) = w4;
      *reinterpret_cast<uint4*>(&sW[wid][lr][16*tt + lg*4]) = pw;
    }
    const int kc = kw0 + 64*c;
#pragma unroll
    for (int ks = 0; ks < 2; ++ks){
      uint4 pa0 = *reinterpret_cast<const uint4*>(&sW[wid][lr][32*ks + lg*8]);
      uint4 pa1 = *reinterpret_cast<const uint4*>(&sW[wid][lr][32*ks + lg*8 + 4]);
      unsigned int pa[8] = {pa0.x,pa0.y,pa0.z,pa0.w,pa1.x,pa1.y,pa1.z,pa1.w};
      bf16x8 ahi, alo;
#pragma unroll
      for (int j = 0; j < 8; ++j){
        ahi[j] = (short)(pa[j] >> 16);
        alo[j] = (short)(pa[j] & 0xFFFFu);
      }
#pragma unroll
      for (int n = 0; n < 4; ++n){
        bf16x8 bhi, blo;
        if constexpr (PACKED){
          const unsigned int* vrow = vtph + (size_t)(16*n + lr) * S + kc + 32*ks + lg*8;
          uint4 p0 = *reinterpret_cast<const uint4*>(vrow);
          uint4 p1 = *reinterpret_cast<const uint4*>(vrow + 4);
          unsigned int pw[8] = {p0.x,p0.y,p0.z,p0.w,p1.x,p1.y,p1.z,p1.w};
#pragma unroll
          for (int j = 0; j < 8; ++j){
            bhi[j] = (short)(pw[j] >> 16);
            blo[j] = (short)(pw[j] & 0xFFFFu);
          }
        } else {
#pragma unroll
          for (int j = 0; j < 8; ++j){
            float x = vh[(size_t)(kc + 32*ks + lg*8 + j) * DD + 16*n + lr];
            short h, l2; split2(x, h, l2);
            bhi[j] = h; blo[j] = l2;
          }
        }
        oacc[n] = __builtin_amdgcn_mfma_f32_16x16x32_bf16(alo, bhi, oacc[n], 0,0,0);
        oacc[n] = __builtin_amdgcn_mfma_f32_16x16x32_bf16(ahi, blo, oacc[n], 0,0,0);
        oacc[n] = __builtin_amdgcn_mfma_f32_16x16x32_bf16(ahi, bhi, oacc[n], 0,0,0);
      }
    }
  }

  // ---- Phase 5: cross-wave reduction of out partials (alias sW)
  float (*sO)[16][68] = reinterpret_cast<float(*)[16][68]>(sW);
#pragma unroll
  for (int n = 0; n < 4; ++n)
#pragma unroll
    for (int r = 0; r < 4; ++r)
      sO[wid][lg*4 + r][16*n + lr] = oacc[n][r];
  __syncthreads();
#pragma unroll
  for (int i = tid; i < 16*64; i += 512){
    int row = i >> 6, d = i & 63;
    float s = 0.f;
#pragma unroll
    for (int w = 0; w < NW; ++w) s += sO[w][row][d];
    oh[(size_t)(q0 + row) * DD + d] = s;
  }
}

extern "C" void kernel_launch(void* const* d_in, const int* in_sizes, int n_in,
                              void* d_out, int out_size, void* d_ws, size_t ws_size,
                              hipStream_t stream) {
  const float* q    = (const float*)d_in[0];
  const float* k    = (const float*)d_in[1];
  const float* v    = (const float*)d_in[2];
  const float* bias = (const float*)d_in[3];
  const float* gb   = (const float*)d_in[4];
  float* out  = (float*)d_out;
  float* wout = (float*)d_out + (size_t)NH * S * DD;

  const size_t nelem = (size_t)NH * S * DD;       // 4.19M
  const size_t need  = 2 * nelem * sizeof(unsigned int);

  dim3 grid(S / 16, NH);
  dim3 block(512);

  if (ws_size >= need){
    unsigned int* kp  = (unsigned int*)d_ws;
    unsigned int* vtp = kp + nelem;
    int n4 = (int)(nelem / 4);
    pack_k_kernel<<<(n4 + 255) / 256, 256, 0, stream>>>(k, kp, n4);
    pack_vt_kernel<<<NH * 32, 256, 0, stream>>>(v, vtp);
    attn_fused_kernel<true><<<grid, block, 0, stream>>>(q, k, v, bias, gb, kp, vtp, out, wout);
  } else {
    attn_fused_kernel<false><<<grid, block, 0, stream>>>(q, k, v, bias, gb, nullptr, nullptr, out, wout);
  }
}